// Round 7
// baseline (858.504 us; speedup 1.0000x reference)
//
#include <hip/hip_runtime.h>
#include <hip/hip_bf16.h>

#define M_DIM 4096
#define N_DIM 8192
#define K_DIM 8192

using bf16x8 = __attribute__((ext_vector_type(8))) short;
using f32x4  = __attribute__((ext_vector_type(4))) float;
using v2s    = __attribute__((ext_vector_type(2))) short;

static __device__ __forceinline__ unsigned short f32_to_bf16_rne(float f) {
    unsigned u = __float_as_uint(f);
    unsigned rounding = 0x7FFFu + ((u >> 16) & 1u);
    u += rounding;
    return (unsigned short)(u >> 16);
}

// ---------------- zero (16B granules) ----------------
__global__ void zero_kernel(float4* __restrict__ p, int n4) {
    int i = blockIdx.x * blockDim.x + threadIdx.x;
    int stride = gridDim.x * blockDim.x;
    float4 z = make_float4(0.f, 0.f, 0.f, 0.f);
    for (; i < n4; i += stride) p[i] = z;
}

// ---------------- scatter-add COO directly into bf16 W ----------------
// W density 6%; duplicates ~0.2% of touched cells -> bf16 accumulation
// error negligible vs the 2.52 threshold.  Native pk_add_bf16 atomic on the
// aligned pair (neighbor half += +0.0 is a no-op); CAS fallback otherwise.
__global__ void scatter_bf16_kernel(const float* __restrict__ vals,
                                    const int* __restrict__ rows,
                                    const int* __restrict__ cols,
                                    unsigned short* __restrict__ W, int n) {
    int i = blockIdx.x * blockDim.x + threadIdx.x;
    if (i >= n) return;
    size_t idx = (size_t)rows[i] * K_DIM + cols[i];
    unsigned* p = (unsigned*)W + (idx >> 1);
    const int hi = (int)(idx & 1);
#if __has_builtin(__builtin_amdgcn_global_atomic_fadd_v2bf16)
    unsigned short h = f32_to_bf16_rne(vals[i]);
    v2s pk;
    pk[0] = hi ? (short)0 : (short)h;
    pk[1] = hi ? (short)h : (short)0;
    __builtin_amdgcn_global_atomic_fadd_v2bf16(
        (__attribute__((address_space(1))) v2s*)p, pk);
#else
    float vf = vals[i];
    unsigned old = __hip_atomic_load(p, __ATOMIC_RELAXED, __HIP_MEMORY_SCOPE_AGENT);
    while (true) {
        unsigned cur = old;
        unsigned short th = hi ? (unsigned short)(cur >> 16)
                               : (unsigned short)(cur & 0xffffu);
        float f = __uint_as_float(((unsigned)th) << 16) + vf;
        unsigned short nh = f32_to_bf16_rne(f);
        unsigned nw = hi ? ((cur & 0x0000ffffu) | ((unsigned)nh << 16))
                         : ((cur & 0xffff0000u) | (unsigned)nh);
        unsigned prev = atomicCAS(p, cur, nw);
        if (prev == cur) break;
        old = prev;
    }
#endif
}

// ---------------- f32 -> bf16 cast (x only) ----------------
__global__ void cvt_bf16_kernel(const float4* __restrict__ src,
                                ushort4* __restrict__ dst, int n4) {
    int i = blockIdx.x * blockDim.x + threadIdx.x;
    int stride = gridDim.x * blockDim.x;
    for (; i < n4; i += stride) {
        float4 v = src[i];
        ushort4 o;
        o.x = f32_to_bf16_rne(v.x);
        o.y = f32_to_bf16_rne(v.y);
        o.z = f32_to_bf16_rne(v.z);
        o.w = f32_to_bf16_rne(v.w);
        dst[i] = o;
    }
}

// ---------------- zero d_out fallback (ws too small diagnostic) ----------------
__global__ void zero_out_kernel(float* __restrict__ p, int n) {
    int i = blockIdx.x * blockDim.x + threadIdx.x;
    int stride = gridDim.x * blockDim.x;
    for (; i < n; i += stride) p[i] = 0.f;
}

// ---------------- bf16 NT GEMM, 256x256 8-phase (T2+T3+T4+T5) ----------------
// C[M][N] = A[M][K] * B[N][K]^T.  BM=BN=256, BK=64, 8 waves (2M x 4N),
// per-wave output 128x64 (acc[8][4] f32x4).  LDS 128 KiB double-buffered.
// r6 change: ALL tile fragments (16 A + 8 B b128 reads) are hoisted into
// registers at phase 0 — phases 1-3 have no LDS reads and no lgkm waits, so
// ds_read latency is paid once per tile (~290 cyc, overlapped with q0's
// stage issue) instead of 4x ~150 cyc with the matrix pipe idle.
// Cross-wave safety: B(t+2) staging (q2) issues after q1's barrier, which
// transitively follows every wave's q0 MFMA, which has a register dep on the
// B reads -> no overwrite-before-read.  vmcnt ledger unchanged:
//   q0: A(t+1) h0 -> db^1   q1: A(t+1) h1 -> db^1
//   q2: B(t+2) h0 -> db     q3: B(t+2) h1 -> db
// boundary vmcnt(4) leaves exactly the B(t+2) pair in flight (T4).
// LDS swizzle (T2, rule #21): slot (row,c) holds global k-chunk c^(row&7);
// staging pre-swizzles the global source, reads apply the same involution.
__global__ __launch_bounds__(512, 2) void gemm_bt(const ushort* __restrict__ A,
                                                  const ushort* __restrict__ B,
                                                  float* __restrict__ C) {
    constexpr int BK = 64;
    constexpr int NT = K_DIM / BK;     // 128 K-tiles
    __shared__ ushort lds[65536];      // 128 KiB

    const int nbn = N_DIM / 256;       // 32
    const int bm = blockIdx.x / nbn;
    const int bn = blockIdx.x % nbn;
    const int brow = bm * 256, bcol = bn * 256;

    const int t    = threadIdx.x;
    const int lane = t & 63;
    const int wid  = t >> 6;           // 0..7
    const int wm   = wid >> 2;         // 0..1 (M)
    const int wn   = wid & 3;          // 0..3 (N)
    const int lrow = lane & 15;
    const int ghi  = lane >> 4;        // 0..3

    // read-side swizzled k-chunk per lane (row&7 == lrow&7)
    const int c0 = (0 + ghi) ^ (lrow & 7);   // ksub 0
    const int c1 = (4 + ghi) ^ (lrow & 7);   // ksub 1

    f32x4  acc[8][4] = {};
    bf16x8 bfr[4][2];                  // B frags, tile-resident

    auto stage_half = [&](int db, int op, int half, int ktile) {
        const ushort* G = (op == 0) ? A : B;
        const int rbase = ((op == 0) ? brow : bcol) + half * 128;
        #pragma unroll
        for (int i = 0; i < 2; ++i) {
            int fl  = i * 512 + t;                 // 0..1023
            int row = fl >> 3;
            int cc  = (fl & 7) ^ (row & 7);
            const ushort* src = G + (size_t)(rbase + row) * K_DIM + ktile * BK + cc * 8;
            __builtin_amdgcn_global_load_lds(
                (const __attribute__((address_space(1))) void*)src,
                (__attribute__((address_space(3))) void*)
                    (&lds[db * 32768 + op * 16384 + half * 8192 + fl * 8]),
                16, 0, 0);
        }
    };

    auto tile_body = [&](int tt, int db, bool stgA, bool stgB, int vm) {
        const ushort* Ah = &lds[db * 32768 + wm * 8192];
        const ushort* Bh = &lds[db * 32768 + 16384 + (wn >> 1) * 8192 + (wn & 1) * 4096];
        const ushort* a0 = Ah + lrow * 64 + c0 * 8;
        const ushort* a1 = Ah + lrow * 64 + c1 * 8;
        const ushort* b0 = Bh + lrow * 64 + c0 * 8;
        const ushort* b1 = Bh + lrow * 64 + c1 * 8;

        // ---- phase 0 head: stage first (keep A-prefetch lead), then hoist
        // ALL tile fragments into registers ----
        if (stgA) stage_half(db ^ 1, 0, 0, tt + 1);
        bf16x8 af[8][2];
        #pragma unroll
        for (int n = 0; n < 4; ++n) {
            bfr[n][0] = *(const bf16x8*)(b0 + n * 1024);
            bfr[n][1] = *(const bf16x8*)(b1 + n * 1024);
        }
        #pragma unroll
        for (int m = 0; m < 8; ++m) {
            af[m][0] = *(const bf16x8*)(a0 + m * 1024);
            af[m][1] = *(const bf16x8*)(a1 + m * 1024);
        }

        #pragma unroll
        for (int q = 0; q < 4; ++q) {
            if (q == 1 && stgA) stage_half(db ^ 1, 0, 1, tt + 1);
            if (q == 2 && stgB) stage_half(db,     1, 0, tt + 2);
            if (q == 3 && stgB) stage_half(db,     1, 1, tt + 2);
            __builtin_amdgcn_s_barrier();
            __builtin_amdgcn_s_setprio(1);
            #pragma unroll
            for (int j = 0; j < 2; ++j)
                #pragma unroll
                for (int n = 0; n < 4; ++n) {
                    acc[2 * q + j][n] = __builtin_amdgcn_mfma_f32_16x16x32_bf16(
                        af[2 * q + j][0], bfr[n][0], acc[2 * q + j][n], 0, 0, 0);
                    acc[2 * q + j][n] = __builtin_amdgcn_mfma_f32_16x16x32_bf16(
                        af[2 * q + j][1], bfr[n][1], acc[2 * q + j][n], 0, 0, 0);
                }
            __builtin_amdgcn_s_setprio(0);
            if (q == 3) {
                if (vm == 4) asm volatile("s_waitcnt vmcnt(4)" ::: "memory");
                else         asm volatile("s_waitcnt vmcnt(0)" ::: "memory");
            }
            __builtin_amdgcn_s_barrier();
        }
    };

    // ---- prologue: tile 0 fully + B(1); drain to 4 (B(1) stays in flight) ----
    stage_half(0, 0, 0, 0);
    stage_half(0, 0, 1, 0);
    stage_half(0, 1, 0, 0);
    stage_half(0, 1, 1, 0);
    stage_half(1, 1, 0, 1);
    stage_half(1, 1, 1, 1);
    asm volatile("s_waitcnt vmcnt(4)" ::: "memory");
    __builtin_amdgcn_s_barrier();

    // ---- main loop: tiles 0..NT-3 with full staging, vmcnt(4) ----
    for (int tt = 0; tt < NT - 2; tt += 2) {
        tile_body(tt,     0, true, true, 4);
        tile_body(tt + 1, 1, true, true, 4);
    }
    // ---- peeled tail: NT-2 stages A(NT-1) only then drains; NT-1 bare ----
    tile_body(NT - 2, 0, true,  false, 0);
    tile_body(NT - 1, 1, false, false, 0);

    // ---- epilogue: C/D layout col=lane&15, row=(lane>>4)*4+r ----
    const int crow0 = brow + wm * 128;
    const int ccol0 = bcol + wn * 64;
    #pragma unroll
    for (int m = 0; m < 8; ++m) {
        #pragma unroll
        for (int n = 0; n < 4; ++n) {
            int col   = ccol0 + n * 16 + lrow;
            int rbase = crow0 + m * 16 + (lane >> 4) * 4;
            #pragma unroll
            for (int r = 0; r < 4; ++r)
                C[(size_t)(rbase + r) * N_DIM + col] = acc[m][n][r];
        }
    }
}

extern "C" void kernel_launch(void* const* d_in, const int* in_sizes, int n_in,
                              void* d_out, int out_size, void* d_ws, size_t ws_size,
                              hipStream_t stream) {
    const float* x    = (const float*)d_in[0];
    const float* vals = (const float*)d_in[1];
    const int* rows   = (const int*)d_in[2];
    const int* cols   = (const int*)d_in[3];
    float* out        = (float*)d_out;
    const int n_items = in_sizes[1];

    const size_t W_BF16_BYTES = (size_t)N_DIM * K_DIM * 2;  // 128 MiB
    const size_t X_BF16_BYTES = (size_t)M_DIM * K_DIM * 2;  //  64 MiB
    const size_t NEEDED = W_BF16_BYTES + X_BF16_BYTES;      // 192 MiB

    if (ws_size < NEEDED) {
        // Diagnostic fallback: clean absmax=126 failure signals ws too small.
        zero_out_kernel<<<2048, 256, 0, stream>>>(out, out_size);
        return;
    }

    char* ws = (char*)d_ws;
    unsigned short* Wb = (unsigned short*)ws;
    ushort* Xb = (ushort*)(ws + W_BF16_BYTES);

    // 1) zero bf16 W (128 MiB; re-zeroed every call: deterministic under replay)
    zero_kernel<<<2048, 256, 0, stream>>>((float4*)Wb,
                                          (int)(W_BF16_BYTES / 16));
    // 2) scatter-add nonzeros directly in bf16 (pk_add_bf16 / CAS fallback)
    scatter_bf16_kernel<<<(n_items + 255) / 256, 256, 0, stream>>>(
        vals, rows, cols, Wb, n_items);
    // 3) cast x to bf16
    cvt_bf16_kernel<<<2048, 256, 0, stream>>>((const float4*)x, (ushort4*)Xb,
                                              (M_DIM * K_DIM) / 4);
    // 4) GEMM: out = Xb (M x K) * Wb (N x K)^T  -- 512 blocks of 512 threads
    gemm_bt<<<(M_DIM / 256) * (N_DIM / 256), 512, 0, stream>>>(
        Xb, (const ushort*)Wb, out);
}

// Round 8
// 615.657 us; speedup vs baseline: 1.3945x; 1.3945x over previous
//
#include <hip/hip_runtime.h>
#include <hip/hip_bf16.h>

#define M_DIM 4096
#define N_DIM 8192
#define K_DIM 8192
#define CAP   768          // bin capacity per W row (mean 488, sigma 22)
#define OVF_CAP 4096

using bf16x8 = __attribute__((ext_vector_type(8))) short;
using f32x4  = __attribute__((ext_vector_type(4))) float;
using v2s    = __attribute__((ext_vector_type(2))) short;

static __device__ __forceinline__ unsigned short f32_to_bf16_rne(float f) {
    unsigned u = __float_as_uint(f);
    unsigned rounding = 0x7FFFu + ((u >> 16) & 1u);
    u += rounding;
    return (unsigned short)(u >> 16);
}

// atomically add bf16 h into W[idx] (overflow path only; ~0 items in practice)
static __device__ __forceinline__ void atomic_add_bf16(unsigned short* W,
                                                       unsigned idx,
                                                       unsigned short h) {
    unsigned* p = (unsigned*)W + (idx >> 1);
    const int hi = (int)(idx & 1);
#if __has_builtin(__builtin_amdgcn_global_atomic_fadd_v2bf16)
    v2s pk;
    pk[0] = hi ? (short)0 : (short)h;
    pk[1] = hi ? (short)h : (short)0;
    __builtin_amdgcn_global_atomic_fadd_v2bf16(
        (__attribute__((address_space(1))) v2s*)p, pk);
#else
    float vf = __uint_as_float(((unsigned)h) << 16);
    unsigned old = __hip_atomic_load(p, __ATOMIC_RELAXED, __HIP_MEMORY_SCOPE_AGENT);
    while (true) {
        unsigned cur = old;
        unsigned short th = hi ? (unsigned short)(cur >> 16)
                               : (unsigned short)(cur & 0xffffu);
        float f = __uint_as_float(((unsigned)th) << 16) + vf;
        unsigned short nh = f32_to_bf16_rne(f);
        unsigned nw = hi ? ((cur & 0x0000ffffu) | ((unsigned)nh << 16))
                         : ((cur & 0xffff0000u) | (unsigned)nh);
        unsigned prev = atomicCAS(p, cur, nw);
        if (prev == cur) break;
        old = prev;
    }
#endif
}

// ---------------- zero (16B granules) ----------------
__global__ void zero_kernel(float4* __restrict__ p, int n4) {
    int i = blockIdx.x * blockDim.x + threadIdx.x;
    int stride = gridDim.x * blockDim.x;
    float4 z = make_float4(0.f, 0.f, 0.f, 0.f);
    for (; i < n4; i += stride) p[i] = z;
}

// ---------------- pass 1: bin items by destination row ----------------
// bins[row][pos] = (col<<16) | bf16(val).  pos via atomicAdd on fill[row]
// (8192 hot L2-resident counters).  Overflow (>=13 sigma, ~impossible) goes
// to a small list applied after row_accum.
__global__ void reorder_kernel(const float* __restrict__ vals,
                               const int* __restrict__ rows,
                               const int* __restrict__ cols,
                               unsigned* __restrict__ bins,
                               unsigned* __restrict__ fill,
                               unsigned* __restrict__ ovf_cnt,
                               uint2* __restrict__ ovf, int n) {
    int i = blockIdx.x * blockDim.x + threadIdx.x;
    if (i >= n) return;
    int r = rows[i], c = cols[i];
    unsigned h = f32_to_bf16_rne(vals[i]);
    unsigned pos = atomicAdd(&fill[r], 1u);
    if (pos < CAP) {
        bins[(size_t)r * CAP + pos] = ((unsigned)c << 16) | h;
    } else {
        unsigned o = atomicAdd(ovf_cnt, 1u);
        if (o < OVF_CAP)
            ovf[o] = make_uint2((unsigned)r * K_DIM + (unsigned)c, h);
    }
}

// ---------------- pass 2: per-row accumulate + write full bf16 row --------
// One block per W row: f32 LDS rowbuf (32 KB), LDS atomics for ~488 items,
// then one coalesced 16 KB row write.  Replaces BOTH the W-zero pass and
// the global atomic scatter; duplicates are summed in f32 before a single
// bf16 rounding (more accurate than the r6 bf16-atomic path).
__global__ __launch_bounds__(256) void row_accum_kernel(
        const unsigned* __restrict__ bins,
        const unsigned* __restrict__ fill,
        unsigned short* __restrict__ W) {
    __shared__ float rowbuf[K_DIM];    // 32 KB
    const int row = blockIdx.x;
    const int tid = threadIdx.x;
    float4* rb4 = (float4*)rowbuf;
    #pragma unroll
    for (int i = 0; i < K_DIM / 4 / 256; ++i)
        rb4[i * 256 + tid] = make_float4(0.f, 0.f, 0.f, 0.f);
    __syncthreads();
    int n = (int)fill[row];
    if (n > CAP) n = CAP;
    const unsigned* seg = bins + (size_t)row * CAP;
    for (int i = tid; i < n; i += 256) {
        unsigned u = seg[i];
        atomicAdd(&rowbuf[u >> 16], __uint_as_float((u & 0xffffu) << 16));
    }
    __syncthreads();
    unsigned* Wrow = (unsigned*)(W + (size_t)row * K_DIM);  // 4096 dwords
    #pragma unroll
    for (int i = 0; i < K_DIM / 2 / 256; ++i) {
        int j = i * 256 + tid;
        unsigned pa = f32_to_bf16_rne(rowbuf[2 * j]);
        unsigned pb = f32_to_bf16_rne(rowbuf[2 * j + 1]);
        Wrow[j] = pa | (pb << 16);
    }
}

// ---------------- pass 3: apply (rare) overflow items ----------------
__global__ void ovf_apply_kernel(const unsigned* __restrict__ ovf_cnt,
                                 const uint2* __restrict__ ovf,
                                 unsigned short* __restrict__ W) {
    unsigned n = *ovf_cnt;
    if (n > OVF_CAP) n = OVF_CAP;
    for (unsigned i = threadIdx.x; i < n; i += blockDim.x)
        atomic_add_bf16(W, ovf[i].x, (unsigned short)ovf[i].y);
}

// ---------------- f32 -> bf16 cast (x only) ----------------
__global__ void cvt_bf16_kernel(const float4* __restrict__ src,
                                ushort4* __restrict__ dst, int n4) {
    int i = blockIdx.x * blockDim.x + threadIdx.x;
    int stride = gridDim.x * blockDim.x;
    for (; i < n4; i += stride) {
        float4 v = src[i];
        ushort4 o;
        o.x = f32_to_bf16_rne(v.x);
        o.y = f32_to_bf16_rne(v.y);
        o.z = f32_to_bf16_rne(v.z);
        o.w = f32_to_bf16_rne(v.w);
        dst[i] = o;
    }
}

// ---------------- zero d_out fallback (ws too small diagnostic) ----------------
__global__ void zero_out_kernel(float* __restrict__ p, int n) {
    int i = blockIdx.x * blockDim.x + threadIdx.x;
    int stride = gridDim.x * blockDim.x;
    for (; i < n; i += stride) p[i] = 0.f;
}

// ---------------- bf16 NT GEMM, 256x256 8-phase (T2+T3+T4+T5) ----------------
// EXACT r6 revert (measured 437 us, 1259 TF, MfmaUtil 56, conflicts 0).
// r7's full fragment hoist REGRESSED (643 us, MfmaUtil 36): 96 fragment
// VGPRs live across 8 barriers/tile defeated the compiler's per-phase
// counted lgkm waits, and phase 0 serialized all 24 reads with no MFMA
// coverage (8 waves barrier-locked, 1 block/CU).  Per-phase reads stay.
__global__ __launch_bounds__(512, 2) void gemm_bt(const ushort* __restrict__ A,
                                                  const ushort* __restrict__ B,
                                                  float* __restrict__ C) {
    constexpr int BK = 64;
    constexpr int NT = K_DIM / BK;     // 128 K-tiles
    __shared__ ushort lds[65536];      // 128 KiB

    const int nbn = N_DIM / 256;       // 32
    const int bm = blockIdx.x / nbn;
    const int bn = blockIdx.x % nbn;
    const int brow = bm * 256, bcol = bn * 256;

    const int t    = threadIdx.x;
    const int lane = t & 63;
    const int wid  = t >> 6;           // 0..7
    const int wm   = wid >> 2;         // 0..1 (M)
    const int wn   = wid & 3;          // 0..3 (N)
    const int lrow = lane & 15;
    const int ghi  = lane >> 4;        // 0..3

    const int c0 = (0 + ghi) ^ (lrow & 7);   // ksub 0
    const int c1 = (4 + ghi) ^ (lrow & 7);   // ksub 1

    f32x4  acc[8][4] = {};
    bf16x8 bfr[4][2];                  // B frags, live across one tile

    auto stage_half = [&](int db, int op, int half, int ktile) {
        const ushort* G = (op == 0) ? A : B;
        const int rbase = ((op == 0) ? brow : bcol) + half * 128;
        #pragma unroll
        for (int i = 0; i < 2; ++i) {
            int fl  = i * 512 + t;                 // 0..1023
            int row = fl >> 3;
            int cc  = (fl & 7) ^ (row & 7);
            const ushort* src = G + (size_t)(rbase + row) * K_DIM + ktile * BK + cc * 8;
            __builtin_amdgcn_global_load_lds(
                (const __attribute__((address_space(1))) void*)src,
                (__attribute__((address_space(3))) void*)
                    (&lds[db * 32768 + op * 16384 + half * 8192 + fl * 8]),
                16, 0, 0);
        }
    };

    auto tile_body = [&](int tt, int db, bool stgA, bool stgB, int vm) {
        const ushort* Ah = &lds[db * 32768 + wm * 8192];
        const ushort* Bh = &lds[db * 32768 + 16384 + (wn >> 1) * 8192 + (wn & 1) * 4096];
        const ushort* a0 = Ah + lrow * 64 + c0 * 8;
        const ushort* a1 = Ah + lrow * 64 + c1 * 8;
        const ushort* b0 = Bh + lrow * 64 + c0 * 8;
        const ushort* b1 = Bh + lrow * 64 + c1 * 8;
        #pragma unroll
        for (int q = 0; q < 4; ++q) {
            bf16x8 af[2][2];
            if (q == 0) {
                #pragma unroll
                for (int n = 0; n < 4; ++n) {
                    bfr[n][0] = *(const bf16x8*)(b0 + n * 1024);
                    bfr[n][1] = *(const bf16x8*)(b1 + n * 1024);
                }
            }
            #pragma unroll
            for (int j = 0; j < 2; ++j) {
                af[j][0] = *(const bf16x8*)(a0 + (2 * q + j) * 1024);
                af[j][1] = *(const bf16x8*)(a1 + (2 * q + j) * 1024);
            }
            if (q == 0 && stgA) stage_half(db ^ 1, 0, 0, tt + 1);
            if (q == 1 && stgA) stage_half(db ^ 1, 0, 1, tt + 1);
            if (q == 2 && stgB) stage_half(db,     1, 0, tt + 2);
            if (q == 3 && stgB) stage_half(db,     1, 1, tt + 2);
            __builtin_amdgcn_s_barrier();
            asm volatile("s_waitcnt lgkmcnt(0)" ::: "memory");
            __builtin_amdgcn_s_setprio(1);
            #pragma unroll
            for (int j = 0; j < 2; ++j)
                #pragma unroll
                for (int n = 0; n < 4; ++n) {
                    acc[2 * q + j][n] = __builtin_amdgcn_mfma_f32_16x16x32_bf16(
                        af[j][0], bfr[n][0], acc[2 * q + j][n], 0, 0, 0);
                    acc[2 * q + j][n] = __builtin_amdgcn_mfma_f32_16x16x32_bf16(
                        af[j][1], bfr[n][1], acc[2 * q + j][n], 0, 0, 0);
                }
            __builtin_amdgcn_s_setprio(0);
            if (q == 3) {
                if (vm == 4) asm volatile("s_waitcnt vmcnt(4)" ::: "memory");
                else         asm volatile("s_waitcnt vmcnt(0)" ::: "memory");
            }
            __builtin_amdgcn_s_barrier();
        }
    };

    // ---- prologue: tile 0 fully + B(1); drain to 4 (B(1) stays in flight) ----
    stage_half(0, 0, 0, 0);
    stage_half(0, 0, 1, 0);
    stage_half(0, 1, 0, 0);
    stage_half(0, 1, 1, 0);
    stage_half(1, 1, 0, 1);
    stage_half(1, 1, 1, 1);
    asm volatile("s_waitcnt vmcnt(4)" ::: "memory");
    __builtin_amdgcn_s_barrier();

    for (int tt = 0; tt < NT - 2; tt += 2) {
        tile_body(tt,     0, true, true, 4);
        tile_body(tt + 1, 1, true, true, 4);
    }
    tile_body(NT - 2, 0, true,  false, 0);
    tile_body(NT - 1, 1, false, false, 0);

    // ---- epilogue: C/D layout col=lane&15, row=(lane>>4)*4+r ----
    const int crow0 = brow + wm * 128;
    const int ccol0 = bcol + wn * 64;
    #pragma unroll
    for (int m = 0; m < 8; ++m) {
        #pragma unroll
        for (int n = 0; n < 4; ++n) {
            int col   = ccol0 + n * 16 + lrow;
            int rbase = crow0 + m * 16 + (lane >> 4) * 4;
            #pragma unroll
            for (int r = 0; r < 4; ++r)
                C[(size_t)(rbase + r) * N_DIM + col] = acc[m][n][r];
        }
    }
}

extern "C" void kernel_launch(void* const* d_in, const int* in_sizes, int n_in,
                              void* d_out, int out_size, void* d_ws, size_t ws_size,
                              hipStream_t stream) {
    const float* x    = (const float*)d_in[0];
    const float* vals = (const float*)d_in[1];
    const int* rows   = (const int*)d_in[2];
    const int* cols   = (const int*)d_in[3];
    float* out        = (float*)d_out;
    const int n_items = in_sizes[1];

    const size_t W_BF16_BYTES = (size_t)N_DIM * K_DIM * 2;        // 128 MiB
    const size_t X_BF16_BYTES = (size_t)M_DIM * K_DIM * 2;        //  64 MiB
    const size_t BINS_BYTES   = (size_t)N_DIM * CAP * 4;          //  24 MiB
    const size_t FILL_BYTES   = (size_t)N_DIM * 4;                //  32 KiB
    const size_t OVF_BYTES    = 16 + (size_t)OVF_CAP * 8;
    const size_t NEEDED = W_BF16_BYTES + X_BF16_BYTES + BINS_BYTES
                        + FILL_BYTES + OVF_BYTES;

    if (ws_size < NEEDED) {
        // Diagnostic fallback: clean absmax=126 failure signals ws too small.
        zero_out_kernel<<<2048, 256, 0, stream>>>(out, out_size);
        return;
    }

    char* ws = (char*)d_ws;
    unsigned short* Wb = (unsigned short*)ws;
    ushort*   Xb      = (ushort*)(ws + W_BF16_BYTES);
    unsigned* bins    = (unsigned*)(ws + W_BF16_BYTES + X_BF16_BYTES);
    unsigned* fill    = (unsigned*)(ws + W_BF16_BYTES + X_BF16_BYTES + BINS_BYTES);
    unsigned* ovf_cnt = fill + N_DIM;
    uint2*    ovf     = (uint2*)(ovf_cnt + 4);

    // 1) zero fill counters + ovf_cnt (32 KiB + 16 B; re-zeroed every call)
    zero_kernel<<<32, 256, 0, stream>>>((float4*)fill,
                                        (int)((FILL_BYTES + 16) / 16));
    // 2) bin items by destination row (packed (col<<16)|bf16(val))
    reorder_kernel<<<(n_items + 255) / 256, 256, 0, stream>>>(
        vals, rows, cols, bins, fill, ovf_cnt, ovf, n_items);
    // 3) per-row accumulate in f32 LDS + write full bf16 W (no W-zero pass)
    row_accum_kernel<<<N_DIM, 256, 0, stream>>>(bins, fill, Wb);
    // 4) apply overflow items (normally zero)
    ovf_apply_kernel<<<1, 256, 0, stream>>>(ovf_cnt, ovf, Wb);
    // 5) cast x to bf16
    cvt_bf16_kernel<<<2048, 256, 0, stream>>>((const float4*)x, (ushort4*)Xb,
                                              (M_DIM * K_DIM) / 4);
    // 6) GEMM: out = Xb (M x K) * Wb (N x K)^T
    gemm_bt<<<(M_DIM / 256) * (N_DIM / 256), 512, 0, stream>>>(
        Xb, (const ushort*)Wb, out);
}